// Round 4
// baseline (204.588 us; speedup 1.0000x reference)
//
#include <hip/hip_runtime.h>

// YOLO v1 loss. pred/target: (16384, 7, 7, 30) fp32.
// R6: persistent pipelined streaming (T3/T4-style counted vmcnt, no barriers).
//   R2/R3/R5 all hit ~70us / ~2.8 TB/s aggregate despite opposite structures;
//   common trait: every wave drains vmcnt to 0 at each tile/block boundary and
//   12544 short-lived waves pay launch/teardown on the critical path.
//   Here: 1280 persistent single-wave blocks (5/CU by LDS), each grid-striding
//   over ~10 tiles of 64 cells. Double-buffered LDS; per tile 16 coalesced
//   global_load_lds (16B); steady-state wait is vmcnt(16) -- next tile's loads
//   NEVER drained mid-loop. Single-wave blocks => zero s_barrier. Per-thread
//   accumulator across tiles; one reduction at the end.

#define CH 30
#define CPT 64                    // cells per tile
#define T 64                      // threads per block (one wave)
#define TILE_F (CPT * CH)         // 1920 floats = 7680 B per tensor
#define TILE_V4 (TILE_F / 4)      // 480 float4 per tensor
#define GRID 1280                 // 5 blocks/CU * 256 CUs

typedef __attribute__((address_space(3))) void* lds_vp;
typedef const __attribute__((address_space(1))) void* gvp;

__device__ __forceinline__ float cell_loss(const float* __restrict__ tb,
                                           const float* __restrict__ pb) {
    const float2* t2 = (const float2*)tb;
    const float2* p2 = (const float2*)pb;
    float2 t[15], p[15];
#pragma unroll
    for (int k = 0; k < 15; ++k) t[k] = t2[k];
#pragma unroll
    for (int k = 0; k < 15; ++k) p[k] = p2[k];

    // channel map: t[0]=(c0,c1) t[1]=(c2,c3) t[2]=(c4,c5) t[3]=(c6,c7)
    //              t[4]=(c8,c9) t[5..14]=(c10..c29)
    const float t4 = t[2].x, t9 = t[4].y;
    const bool coo = t4 > 0.0f;

    // no-object loss (weight 0.5)
    const float d4 = p[2].x - t4;
    const float d9 = p[4].y - t9;
    float sum = coo ? 0.0f : 0.5f * (d4 * d4 + d9 * d9);

    if (coo) {
        // class loss (channels 10..29)
        float cl = 0.0f;
#pragma unroll
        for (int k = 0; k < 10; ++k) {
            const float dx = p[5 + k].x - t[5 + k].x;
            const float dy = p[5 + k].y - t[5 + k].y;
            cl += dx * dx + dy * dy;
        }
        sum += cl;

        // target box 0 corners (reference's exact math incl. inverted inter)
        const float tltx = t[0].x - 0.5f * t[1].x;
        const float tlty = t[0].y - 0.5f * t[1].y;
        const float trbx = t[0].x + 0.5f * t[1].x;
        const float trby = t[0].y + 0.5f * t[1].y;
        const float area2 = (trbx - tltx) * (trby - tlty);

        // pred box 0: ch 0..4, pred box 1: ch 5..9
        const float b0x = p[0].x, b0y = p[0].y, b0w = p[1].x, b0h = p[1].y;
        const float b1x = p[2].y, b1y = p[3].x, b1w = p[3].y, b1h = p[4].x;

        float iou0, iou1;
        {
            const float pltx = b0x - 0.5f * b0w, plty = b0y - 0.5f * b0h;
            const float prbx = b0x + 0.5f * b0w, prby = b0y + 0.5f * b0h;
            const float ltx = fmaxf(pltx, tltx), lty = fmaxf(plty, tlty);
            const float rbx = fminf(prbx, trbx), rby = fminf(prby, trby);
            const float inter = ((rbx - ltx < 0.0f) ? 1.0f : 0.0f) *
                                ((rby - lty < 0.0f) ? 1.0f : 0.0f);
            const float area1 = (prbx - pltx) * (prby - plty);
            iou0 = inter / (area1 + area2 - inter);
        }
        {
            const float pltx = b1x - 0.5f * b1w, plty = b1y - 0.5f * b1h;
            const float prbx = b1x + 0.5f * b1w, prby = b1y + 0.5f * b1h;
            const float ltx = fmaxf(pltx, tltx), lty = fmaxf(plty, tlty);
            const float rbx = fminf(prbx, trbx), rby = fminf(prby, trby);
            const float inter = ((rbx - ltx < 0.0f) ? 1.0f : 0.0f) *
                                ((rby - lty < 0.0f) ? 1.0f : 0.0f);
            const float area1 = (prbx - pltx) * (prby - plty);
            iou1 = inter / (area1 + area2 - inter);
        }
        // jnp.argmax first-index tie-break: idx=1 only if strictly greater
        const bool idx1 = iou1 > iou0;

        // responsible pred box (static selects, no dynamic reg indexing)
        const float rpx = idx1 ? b1x : b0x;
        const float rpy = idx1 ? b1y : b0y;
        const float rpw = idx1 ? b1w : b0w;
        const float rph = idx1 ? b1h : b0h;
        const float rpc = idx1 ? p[4].y : p[2].x;
        // responsible target box
        const float rtx = idx1 ? t[2].y : t[0].x;
        const float rty = idx1 ? t[3].x : t[0].y;
        const float rtw = idx1 ? t[3].y : t[1].x;
        const float rth = idx1 ? t[4].x : t[1].y;
        const float rtc = idx1 ? t[4].y : t[2].x;

        // contain loss (weight 1)
        const float dc = rpc - rtc;
        sum += dc * dc;

        // localization loss (weight 5)
        const float dx = rpx - rtx;
        const float dy = rpy - rty;
        const float dw = sqrtf(rpw) - sqrtf(rtw);
        const float dh = sqrtf(rph) - sqrtf(rth);
        sum += 5.0f * (dx * dx + dy * dy + dw * dw + dh * dh);
    }
    return sum;
}

__global__ __launch_bounds__(T)
void yolo_partial(const float* __restrict__ pred,
                  const float* __restrict__ targ,
                  float* __restrict__ partial, int ntiles) {
    __shared__ float buf0[2 * TILE_F];
    __shared__ float buf1[2 * TILE_F];

    const int tid = threadIdx.x;
    const int bid = blockIdx.x;

    // tiles handled by this block: t = bid + k*GRID, k = 0..nt-1
    const int nt = (bid < ntiles) ? ((ntiles - bid + GRID - 1) / GRID) : 0;

    // stage tile t (both tensors) into dst; 16 global_load_lds per thread
    auto stage = [&](float* dst, int t) {
        const float4* gt = (const float4*)targ + (long long)t * TILE_V4;
        const float4* gp = (const float4*)pred + (long long)t * TILE_V4;
#pragma unroll
        for (int k = 0; k < 8; ++k) {
            const int v = tid + k * T;
            if (v < TILE_V4)
                __builtin_amdgcn_global_load_lds((gvp)(gt + v),
                                                 (lds_vp)(dst + 4 * v), 16, 0, 0);
        }
#pragma unroll
        for (int k = 0; k < 8; ++k) {
            const int v = tid + k * T;
            if (v < TILE_V4)
                __builtin_amdgcn_global_load_lds((gvp)(gp + v),
                                                 (lds_vp)(dst + TILE_F + 4 * v),
                                                 16, 0, 0);
        }
    };

    float acc = 0.0f;
    if (nt > 0) stage(buf0, bid);
    if (nt > 1) stage(buf1, bid + GRID);

    for (int k = 0; k < nt; ++k) {
        if ((k & 1) == 0) {
            // steady state: 32 outstanding (tiles k, k+1); keep k+1 in flight
            if (k + 1 < nt) asm volatile("s_waitcnt vmcnt(16)" ::: "memory");
            else            asm volatile("s_waitcnt vmcnt(0)"  ::: "memory");
            acc += cell_loss(buf0 + tid * CH, buf0 + TILE_F + tid * CH);
            asm volatile("s_waitcnt lgkmcnt(0)" ::: "memory"); // reads retired
            if (k + 2 < nt) stage(buf0, bid + (k + 2) * GRID);
        } else {
            if (k + 1 < nt) asm volatile("s_waitcnt vmcnt(16)" ::: "memory");
            else            asm volatile("s_waitcnt vmcnt(0)"  ::: "memory");
            acc += cell_loss(buf1 + tid * CH, buf1 + TILE_F + tid * CH);
            asm volatile("s_waitcnt lgkmcnt(0)" ::: "memory");
            if (k + 2 < nt) stage(buf1, bid + (k + 2) * GRID);
        }
    }

    // single-wave reduction: shuffle only, no barrier
#pragma unroll
    for (int off = 32; off > 0; off >>= 1)
        acc += __shfl_down(acc, off, 64);
    if (tid == 0) partial[bid] = acc;
}

__global__ __launch_bounds__(256)
void yolo_reduce(const float* __restrict__ partial, int n, float* __restrict__ out) {
    __shared__ float wave_sums[4];
    float s = 0.0f;
    const int n4 = n >> 2;
    const float4* p4 = (const float4*)partial;
    for (int v = threadIdx.x; v < n4; v += 256) {
        const float4 x = p4[v];
        s += (x.x + x.y) + (x.z + x.w);
    }
    // tail (n not multiple of 4)
    for (int v = (n4 << 2) + threadIdx.x; v < n; v += 256)
        s += partial[v];
#pragma unroll
    for (int off = 32; off > 0; off >>= 1)
        s += __shfl_down(s, off, 64);
    const int wave = threadIdx.x >> 6;
    const int lane = threadIdx.x & 63;
    if (lane == 0) wave_sums[wave] = s;
    __syncthreads();
    if (threadIdx.x == 0) {
        const float tot = wave_sums[0] + wave_sums[1] + wave_sums[2] + wave_sums[3];
        out[0] = tot * (1.0f / 16384.0f);
    }
}

extern "C" void kernel_launch(void* const* d_in, const int* in_sizes, int n_in,
                              void* d_out, int out_size, void* d_ws, size_t ws_size,
                              hipStream_t stream) {
    const float* pred = (const float*)d_in[0];
    const float* targ = (const float*)d_in[1];
    float* out = (float*)d_out;
    float* partial = (float*)d_ws;

    const int n_cells = in_sizes[0] / CH;              // 802816
    const int ntiles = n_cells / CPT;                  // 12544

    yolo_partial<<<GRID, T, 0, stream>>>(pred, targ, partial, ntiles);
    yolo_reduce<<<1, 256, 0, stream>>>(partial, GRID, out);
}